// Round 1
// baseline (8109.957 us; speedup 1.0000x reference)
//
#include <hip/hip_runtime.h>
#include <stdint.h>

// ---------------- problem constants ----------------
constexpr int   WSZ   = 7;
constexpr int   NN    = 49;          // tokens per window
constexpr int   NHEAD = 3;
constexpr int   DIMC  = 96;
constexpr int   HDIM  = 32;
constexpr int   HHH   = 224;
constexpr int   NWIN  = 32;          // windows per side
constexpr int   LTOK  = HHH * HHH;   // 50176 tokens per batch image
constexpr int   BATCH = 16;
constexpr int   SHIFT = 3;
constexpr float QSCALE = 0.17677669529663687f;   // 32^-0.5
constexpr size_t YCOUNT = (size_t)BATCH * LTOK * DIMC;   // 77,070,336 floats

// ---------------- bf16 helpers ----------------
__device__ __forceinline__ float bf2f(unsigned short u) {
    union { unsigned int i; float f; } c; c.i = ((unsigned int)u) << 16; return c.f;
}
__device__ __forceinline__ unsigned short f2bf(float f) {
    union { float f; unsigned int i; } c; c.f = f;
    unsigned int r = c.i + 0x7fffu + ((c.i >> 16) & 1u);   // round-to-nearest-even
    return (unsigned short)(r >> 16);
}

// ---------------- LDS layout for attention kernel ----------------
// region QKV : bf16 [49][292]  = 28,616 B   (phase 0-2 alias: x-tile f32 [49][100]=19,600 B;
//                                             phase 5-6 alias: w_proj^T bf16 [96][100]=19,200 B)
// region H   : f32  [49][100]  = 19,600 B   (LN output; phase 4+ alias: attn-out f32 [49][100])
// region ATT : f32  [49][49]   =  9,604 B
// region RPB : f32  [169][3]   =  2,028 B
// region LIDX: i32  [49]       =    196 B
constexpr int QKV_OFF  = 0;
constexpr int H_OFF    = 28624;
constexpr int ATT_OFF  = 48224;
constexpr int RPB_OFF  = 57840;
constexpr int LIDX_OFF = 59872;
constexpr int SMEM_SZ  = 60080;

__launch_bounds__(256, 2)
__global__ void attn_kernel(const float* __restrict__ x,
                            const float* __restrict__ w_qkv,
                            const float* __restrict__ b_qkv,
                            const float* __restrict__ w_proj,
                            const float* __restrict__ b_proj,
                            const float* __restrict__ rpb,
                            const float* __restrict__ g1,
                            const float* __restrict__ be1,
                            float* __restrict__ out)
{
    __shared__ __align__(16) char smem[SMEM_SZ];
    unsigned short* qkv = (unsigned short*)(smem + QKV_OFF);   // [49][292] bf16
    float*  h_s    = (float*)(smem + H_OFF);                   // [49][100]
    float*  attn_s = (float*)(smem + ATT_OFF);                 // [49][49]
    float*  rpb_s  = (float*)(smem + RPB_OFF);                 // [169][3]
    int*    lidx   = (int*)(smem + LIDX_OFF);                  // [49]

    const int tid = threadIdx.x;
    const int w   = blockIdx.x;
    const int b   = w >> 10;
    const int wr  = (w >> 5) & 31;
    const int wc  = w & 31;

    // ---- phase 0: token -> flat index map, stage rpb table ----
    if (tid < NN) {
        int r = tid / WSZ, c = tid % WSZ;
        int gy = (wr * WSZ + r + SHIFT) % HHH;
        int gx = (wc * WSZ + c + SHIFT) % HHH;
        lidx[tid] = gy * HHH + gx;
    }
    for (int i = tid; i < 169 * NHEAD; i += 256) rpb_s[i] = rpb[i];
    __syncthreads();

    // ---- phase 1: stage x tile (alias of qkv region) ----
    float* xt = (float*)(smem + QKV_OFF);   // [49][100]
    const float* xb = x + (size_t)b * LTOK * DIMC;
    for (int i = tid; i < NN * DIMC; i += 256) {
        int n = i / DIMC, cc = i % DIMC;
        xt[n * 100 + cc] = xb[(size_t)lidx[n] * DIMC + cc];
    }
    __syncthreads();

    // ---- phase 2: LN1 (one thread per token) ----
    if (tid < NN) {
        float s = 0.f, ss = 0.f;
        for (int k = 0; k < DIMC; k++) { float v = xt[tid * 100 + k]; s += v; ss += v * v; }
        float mu  = s * (1.f / 96.f);
        float var = ss * (1.f / 96.f) - mu * mu;
        float inv = rsqrtf(var + 1e-5f);
        for (int k = 0; k < DIMC; k++) {
            float v = (xt[tid * 100 + k] - mu) * inv;
            h_s[tid * 100 + k] = v * g1[k] + be1[k];
        }
    }
    __syncthreads();

    // ---- phase 3: QKV projection, register-tiled (thread j owns column j) ----
    // overwrites the x-tile alias; reads h_s only.
    for (int jj = 0; jj < 3 * DIMC; jj += 256) {
        int j = jj + tid;
        if (j < 3 * DIMC) {
            float acc[NN];
            float bj = b_qkv[j];
#pragma unroll
            for (int t = 0; t < NN; t++) acc[t] = bj;
            for (int k4 = 0; k4 < DIMC; k4 += 4) {
                float w0 = w_qkv[(k4 + 0) * 288 + j];
                float w1 = w_qkv[(k4 + 1) * 288 + j];
                float w2 = w_qkv[(k4 + 2) * 288 + j];
                float w3 = w_qkv[(k4 + 3) * 288 + j];
#pragma unroll
                for (int t = 0; t < NN; t++) {
                    const float4 hv = *(const float4*)&h_s[t * 100 + k4];
                    acc[t] = fmaf(hv.x, w0, acc[t]);
                    acc[t] = fmaf(hv.y, w1, acc[t]);
                    acc[t] = fmaf(hv.z, w2, acc[t]);
                    acc[t] = fmaf(hv.w, w3, acc[t]);
                }
            }
            float sc = (j < DIMC) ? QSCALE : 1.f;   // fold q*scale
#pragma unroll
            for (int t = 0; t < NN; t++) qkv[t * 292 + j] = f2bf(acc[t] * sc);
        }
    }
    __syncthreads();

    // ---- phase 4: per-head attention ----
    float* aout_s = (float*)(smem + H_OFF);   // attn-out accumulator [49][100] (h_s dead)
    for (int h = 0; h < NHEAD; h++) {
        // 4a: logits = (q*scale) . k + bias
        for (int idx = tid; idx < NN * NN; idx += 256) {
            int n = idx / NN, m = idx % NN;
            const unsigned short* qr = &qkv[n * 292 + h * HDIM];
            const unsigned short* kr = &qkv[m * 292 + DIMC + h * HDIM];
            float acc = 0.f;
#pragma unroll
            for (int d4 = 0; d4 < HDIM; d4 += 4) {
                ushort4 qu = *(const ushort4*)&qr[d4];
                ushort4 ku = *(const ushort4*)&kr[d4];
                acc = fmaf(bf2f(qu.x), bf2f(ku.x), acc);
                acc = fmaf(bf2f(qu.y), bf2f(ku.y), acc);
                acc = fmaf(bf2f(qu.z), bf2f(ku.z), acc);
                acc = fmaf(bf2f(qu.w), bf2f(ku.w), acc);
            }
            int rn = n / WSZ, cn = n % WSZ, rm = m / WSZ, cm = m % WSZ;
            int rel = (rn - rm + 6) * 13 + (cn - cm + 6);
            attn_s[idx] = acc + rpb_s[rel * NHEAD + h];
        }
        __syncthreads();

        // 4b: softmax per row (one thread per row)
        if (tid < NN) {
            float mx = -1e30f;
            for (int m = 0; m < NN; m++) mx = fmaxf(mx, attn_s[tid * NN + m]);
            float s = 0.f;
            for (int m = 0; m < NN; m++) {
                float e = __expf(attn_s[tid * NN + m] - mx);
                attn_s[tid * NN + m] = e; s += e;
            }
            float inv = 1.f / s;
            for (int m = 0; m < NN; m++) attn_s[tid * NN + m] *= inv;
        }
        __syncthreads();

        // 4c: write probs to output (coalesced)
        float* ag = out + YCOUNT + ((size_t)w * NHEAD + h) * NN * NN;
        for (int idx = tid; idx < NN * NN; idx += 256) ag[idx] = attn_s[idx];

        // 4d: PV -> attn-out columns [h*32 .. h*32+31]
        for (int u = tid; u < NN * (HDIM / 4); u += 256) {    // 392 units
            int n = u / (HDIM / 4), d4 = (u % (HDIM / 4)) * 4;
            float a0 = 0.f, a1 = 0.f, a2 = 0.f, a3 = 0.f;
            for (int m = 0; m < NN; m++) {
                float p = attn_s[n * NN + m];
                ushort4 vu = *(const ushort4*)&qkv[m * 292 + 2 * DIMC + h * HDIM + d4];
                a0 = fmaf(p, bf2f(vu.x), a0);
                a1 = fmaf(p, bf2f(vu.y), a1);
                a2 = fmaf(p, bf2f(vu.z), a2);
                a3 = fmaf(p, bf2f(vu.w), a3);
            }
            *(float4*)&aout_s[n * 100 + h * HDIM + d4] = make_float4(a0, a1, a2, a3);
        }
        __syncthreads();
    }

    // ---- phase 5: stage w_proj^T (bf16) into qkv region (now dead) ----
    unsigned short* wp = (unsigned short*)(smem + QKV_OFF);   // [96][100], wp[c][k]
    for (int i = tid; i < DIMC * DIMC; i += 256) {
        int cc = i / DIMC, kk = i % DIMC;
        wp[cc * 100 + kk] = f2bf(w_proj[kk * DIMC + cc]);
    }
    __syncthreads();

    // ---- phase 6: proj + bias + residual, scatter back ----
    for (int idx = tid; idx < NN * DIMC; idx += 256) {
        int n = idx / DIMC, cc = idx % DIMC;
        float acc = b_proj[cc];
#pragma unroll
        for (int k4 = 0; k4 < DIMC; k4 += 4) {
            const float4 av = *(const float4*)&aout_s[n * 100 + k4];
            ushort4 wv = *(const ushort4*)&wp[cc * 100 + k4];
            acc = fmaf(av.x, bf2f(wv.x), acc);
            acc = fmaf(av.y, bf2f(wv.y), acc);
            acc = fmaf(av.z, bf2f(wv.z), acc);
            acc = fmaf(av.w, bf2f(wv.w), acc);
        }
        size_t gi = ((size_t)b * LTOK + lidx[n]) * DIMC + cc;
        out[gi] = x[gi] + acc;    // y1 = shortcut + attn branch
    }
}

// ---------------- MLP kernel: in-place y += fc2(gelu(fc1(LN2(y)))) ----------------
constexpr int MT = 32;   // tokens per block

__launch_bounds__(384, 2)
__global__ void mlp_kernel(float* __restrict__ y,
                           const float* __restrict__ g2,
                           const float* __restrict__ be2,
                           const float* __restrict__ wf1,
                           const float* __restrict__ bf1,
                           const float* __restrict__ wf2,
                           const float* __restrict__ bf2v)
{
    __shared__ __align__(16) float yt[MT * 100];
    __shared__ __align__(16) float h2[MT * 100];
    __shared__ __align__(16) unsigned short ms[MT * 384];

    const int tid = threadIdx.x;
    const size_t t0 = (size_t)blockIdx.x * MT;

    // stage y tile
    for (int i = tid; i < MT * DIMC; i += 384) {
        int t = i / DIMC, c = i % DIMC;
        yt[t * 100 + c] = y[(t0 + t) * DIMC + c];
    }
    __syncthreads();

    // LN2
    if (tid < MT) {
        float s = 0.f, ss = 0.f;
        for (int k = 0; k < DIMC; k++) { float v = yt[tid * 100 + k]; s += v; ss += v * v; }
        float mu  = s * (1.f / 96.f);
        float var = ss * (1.f / 96.f) - mu * mu;
        float inv = rsqrtf(var + 1e-5f);
        for (int k = 0; k < DIMC; k++) {
            float v = (yt[tid * 100 + k] - mu) * inv;
            h2[tid * 100 + k] = v * g2[k] + be2[k];
        }
    }
    __syncthreads();

    // fc1 + exact GELU: thread j owns hidden column j (384 threads)
    {
        const int j = tid;
        float acc[MT];
        float bj = bf1[j];
#pragma unroll
        for (int t = 0; t < MT; t++) acc[t] = bj;
        for (int k4 = 0; k4 < DIMC; k4 += 4) {
            float w0 = wf1[(k4 + 0) * 384 + j];
            float w1 = wf1[(k4 + 1) * 384 + j];
            float w2 = wf1[(k4 + 2) * 384 + j];
            float w3 = wf1[(k4 + 3) * 384 + j];
#pragma unroll
            for (int t = 0; t < MT; t++) {
                const float4 hv = *(const float4*)&h2[t * 100 + k4];
                acc[t] = fmaf(hv.x, w0, acc[t]);
                acc[t] = fmaf(hv.y, w1, acc[t]);
                acc[t] = fmaf(hv.z, w2, acc[t]);
                acc[t] = fmaf(hv.w, w3, acc[t]);
            }
        }
#pragma unroll
        for (int t = 0; t < MT; t++) {
            float v = acc[t];
            float gl = 0.5f * v * (1.0f + erff(v * 0.70710678118654752f));
            ms[t * 384 + j] = f2bf(gl);
        }
    }
    __syncthreads();

    // fc2 + residual: thread (jc = tid%96) owns out column, group g = tid/96 owns 8 tokens
    {
        const int jc = tid % 96, g = tid / 96;
        float a2[8];
        float bj = bf2v[jc];
#pragma unroll
        for (int t = 0; t < 8; t++) a2[t] = bj;
        for (int k4 = 0; k4 < 384; k4 += 4) {
            float w0 = wf2[(k4 + 0) * 96 + jc];
            float w1 = wf2[(k4 + 1) * 96 + jc];
            float w2 = wf2[(k4 + 2) * 96 + jc];
            float w3 = wf2[(k4 + 3) * 96 + jc];
#pragma unroll
            for (int tt = 0; tt < 8; tt++) {
                int t = g * 8 + tt;
                ushort4 mu4 = *(const ushort4*)&ms[t * 384 + k4];
                a2[tt] = fmaf(bf2f(mu4.x), w0, a2[tt]);
                a2[tt] = fmaf(bf2f(mu4.y), w1, a2[tt]);
                a2[tt] = fmaf(bf2f(mu4.z), w2, a2[tt]);
                a2[tt] = fmaf(bf2f(mu4.w), w3, a2[tt]);
            }
        }
#pragma unroll
        for (int tt = 0; tt < 8; tt++) {
            int t = g * 8 + tt;
            y[(t0 + t) * DIMC + jc] = yt[t * 100 + jc] + a2[tt];
        }
    }
}

// ---------------- launcher ----------------
extern "C" void kernel_launch(void* const* d_in, const int* in_sizes, int n_in,
                              void* d_out, int out_size, void* d_ws, size_t ws_size,
                              hipStream_t stream) {
    const float* x      = (const float*)d_in[0];
    const float* w_qkv  = (const float*)d_in[1];
    const float* b_qkv  = (const float*)d_in[2];
    const float* w_proj = (const float*)d_in[3];
    const float* b_proj = (const float*)d_in[4];
    const float* rpb    = (const float*)d_in[5];
    const float* g1     = (const float*)d_in[6];
    const float* be1    = (const float*)d_in[7];
    const float* g2     = (const float*)d_in[8];
    const float* be2    = (const float*)d_in[9];
    const float* wf1    = (const float*)d_in[10];
    const float* bf1    = (const float*)d_in[11];
    const float* wf2    = (const float*)d_in[12];
    const float* bf2v   = (const float*)d_in[13];
    float* out = (float*)d_out;

    const int nwin_total = BATCH * NWIN * NWIN;          // 16384
    attn_kernel<<<nwin_total, 256, 0, stream>>>(x, w_qkv, b_qkv, w_proj, b_proj,
                                                rpb, g1, be1, out);

    const int ntok_blocks = (BATCH * LTOK) / MT;         // 25088
    mlp_kernel<<<ntok_blocks, 384, 0, stream>>>(out, g2, be2, wf1, bf1, wf2, bf2v);
}